// Round 10
// baseline (91.468 us; speedup 1.0000x reference)
//
#include <hip/hip_runtime.h>

// Problem constants (from reference)
#define Bsz  32
#define Nn   512
#define DIN  256
#define DSC  32
#define Cc   48
#define Hh   152
#define Ww   160
#define HW   (Hh * Ww)        // 24320
#define COUT (Cc + DSC)       // 80
#define HALF (HW / 2)         // 12160 cells per half-plane
#define HP4  (HALF / 4)       // 3040 float4 per half-plane

// Copy geometry: linear over spatial (one contiguous 149 MB stream).
#define CP_N4     (Bsz * Cc * (HW / 4))   // 9,338,880 float4 to copy
#define CP_GRID   2048
#define CP_THREAD 256
#define CP_STRIDE (CP_GRID * CP_THREAD)   // 524,288 f4 = 8 MB sliding window
#define SLAB4     (Cc * (HW / 4))         // 291,840 f4 per batch copy-slab
#define SC4       ((COUT - Cc) * (HW / 4))// 194,560 f4 dst slab shift per batch
#define PR_GRID   ((Bsz * Nn) / 32)       // 512 proj blocks
#define GA_GRID   (Bsz * DSC * 2)         // 2048 gather blocks

// Native clang vector type — required by __builtin_nontemporal_*.
typedef float f4 __attribute__((ext_vector_type(4)));

// ---------------------------------------------------------------------------
// K1: proj = relu(emb @ W + b) * mask -> projws; cell index -> idxws.
// NO LDS: W rows read direct (L1/L2-hot 32 KB; per k, lanes 0..7 fetch one
// contiguous 128 B segment, other lane-groups broadcast), emb row f4 reads
// broadcast across the 8 lanes of an entity. No barrier, low VGPR -> high
// occupancy hides global latency.
// ---------------------------------------------------------------------------
__global__ __launch_bounds__(256) void proj_kernel(
    const float* __restrict__ emb, const float* __restrict__ mask,
    const int* __restrict__ loc, const float* __restrict__ Wp,
    const float* __restrict__ bp, float* __restrict__ projws,
    int* __restrict__ idxws) {

    const int tid  = threadIdx.x;
    const int g    = tid >> 3;            // entity within block
    const int dq4  = tid & 7;             // f4-column in W / proj row
    const int ent  = blockIdx.x * 32 + g;

    const f4* __restrict__ erow = (const f4*)(emb + (size_t)ent * DIN);
    const f4* __restrict__ wf4  = (const f4*)Wp;   // W[k][4*dq4] at k*8+dq4

    const f4 bv = ((const f4*)bp)[dq4];
    float ax = bv.x, ay = bv.y, az = bv.z, aw = bv.w;

    #pragma unroll 4
    for (int k4 = 0; k4 < DIN / 4; ++k4) {
        const f4 ev = erow[k4];
        const int k = k4 * 4;
        const f4 w0 = wf4[(k + 0) * 8 + dq4];
        const f4 w1 = wf4[(k + 1) * 8 + dq4];
        const f4 w2 = wf4[(k + 2) * 8 + dq4];
        const f4 w3 = wf4[(k + 3) * 8 + dq4];
        ax = fmaf(ev.x, w0.x, fmaf(ev.y, w1.x, fmaf(ev.z, w2.x, fmaf(ev.w, w3.x, ax))));
        ay = fmaf(ev.x, w0.y, fmaf(ev.y, w1.y, fmaf(ev.z, w2.y, fmaf(ev.w, w3.y, ay))));
        az = fmaf(ev.x, w0.z, fmaf(ev.y, w1.z, fmaf(ev.z, w2.z, fmaf(ev.w, w3.z, az))));
        aw = fmaf(ev.x, w0.w, fmaf(ev.y, w1.w, fmaf(ev.z, w2.w, fmaf(ev.w, w3.w, aw))));
    }

    const float m = mask[ent];
    f4 r;
    r.x = fmaxf(ax, 0.f) * m;
    r.y = fmaxf(ay, 0.f) * m;
    r.z = fmaxf(az, 0.f) * m;
    r.w = fmaxf(aw, 0.f) * m;
    ((f4*)projws)[(size_t)ent * (DSC / 4) + dq4] = r;

    if (dq4 == 0) {
        int y = loc[2 * ent + 0];
        int x = loc[2 * ent + 1];
        y = min(max(y, 0), Hh - 1);
        x = min(max(x, 0), Ww - 1);
        idxws[ent] = y * Ww + x;
    }
}

// ---------------------------------------------------------------------------
// K2: copy + gather MERGED (even bid = copy, odd bid = gather) so both
// output write streams run concurrently and gather's latency phases hide
// under the copy's BW saturation.
//  copy:   grid-stride sliding window, CACHED loads (spatial L3-resident
//          across replays) + NT stores.
//  gather: (b, channel c, half-plane): zero 48.6 KB LDS acc, scan 512
//          entity cells, LDS-atomicAdd in-range proj values (zero skipped —
//          exact), dump as one contiguous NT stream.
// LDS 48.6 KB -> 3 blocks/CU = 12 waves/CU (fill needs ~3 waves/CU for 7 TB/s).
// ---------------------------------------------------------------------------
__global__ __launch_bounds__(256) void copy_gather_kernel(
    const float* __restrict__ spatial, const float* __restrict__ projws,
    const int* __restrict__ idxws, float* __restrict__ out) {

    __shared__ float facc[HALF];          // 48,640 B

    const int bid = blockIdx.x;
    const int tid = threadIdx.x;

    if ((bid & 1) == 0) {                 // ---- copy (even bids) ----
        const f4* __restrict__ src = (const f4*)spatial;
        f4* __restrict__       dst = (f4*)out;
        unsigned i = (unsigned)(bid >> 1) * CP_THREAD + tid;
        #pragma unroll 1
        for (int k = 0; k < 4; ++k) {     // 16 of 17 rounds, 4-deep
            const unsigned i0 = i, i1 = i + CP_STRIDE,
                           i2 = i + 2 * CP_STRIDE, i3 = i + 3 * CP_STRIDE;
            const f4 a0 = src[i0];
            const f4 a1 = src[i1];
            const f4 a2 = src[i2];
            const f4 a3 = src[i3];
            __builtin_nontemporal_store(a0, dst + i0 + (i0 / (unsigned)SLAB4) * SC4);
            __builtin_nontemporal_store(a1, dst + i1 + (i1 / (unsigned)SLAB4) * SC4);
            __builtin_nontemporal_store(a2, dst + i2 + (i2 / (unsigned)SLAB4) * SC4);
            __builtin_nontemporal_store(a3, dst + i3 + (i3 / (unsigned)SLAB4) * SC4);
            i += 4 * CP_STRIDE;
        }
        {                                 // round 17
            const f4 a = src[i];
            __builtin_nontemporal_store(a, dst + i + (i / (unsigned)SLAB4) * SC4);
            i += CP_STRIDE;
        }
        if (i < (unsigned)CP_N4) {        // partial tail
            const f4 a = src[i];
            __builtin_nontemporal_store(a, dst + i + (i / (unsigned)SLAB4) * SC4);
        }
        return;
    }

    // ---- gather (odd bids) ----
    const int gid = bid >> 1;             // 0 .. GA_GRID-1, dst-address order
    const int b   = gid >> 6;
    const int c   = (gid >> 1) & 31;
    const int lo  = (gid & 1) * HALF;

    for (int i = tid; i < HP4; i += 256) ((f4*)facc)[i] = (f4)(0.f);
    __syncthreads();

    const int2 v = ((const int2*)(idxws + b * Nn))[tid];  // entities 2t, 2t+1
    {
        const int r0 = v.x - lo;
        if ((unsigned)r0 < (unsigned)HALF) {
            const float p = projws[((size_t)b * Nn + 2 * tid) * DSC + c];
            if (p != 0.f) atomicAdd(&facc[r0], p);
        }
        const int r1 = v.y - lo;
        if ((unsigned)r1 < (unsigned)HALF) {
            const float p = projws[((size_t)b * Nn + 2 * tid + 1) * DSC + c];
            if (p != 0.f) atomicAdd(&facc[r1], p);
        }
    }
    __syncthreads();

    f4* obase = (f4*)(out + ((size_t)(b * COUT + Cc + c)) * HW + lo);
    for (int i = tid; i < HP4; i += 256)
        __builtin_nontemporal_store(((const f4*)facc)[i], obase + i);
}

// ---------------------------------------------------------------------------
// Fallback path (only if ws_size too small): R1 design.
// ---------------------------------------------------------------------------
__global__ __launch_bounds__(256) void init_out_kernel(
    const float* __restrict__ spatial, float* __restrict__ out) {
    const int plane = blockIdx.x;
    const int b = plane / COUT;
    const int c = plane % COUT;
    f4* dst = (f4*)(out + (size_t)plane * HW);
    if (c < Cc) {
        const f4* src = (const f4*)(spatial + ((size_t)b * Cc + c) * HW);
        for (int i = threadIdx.x; i < HW / 4; i += blockDim.x) dst[i] = src[i];
    } else {
        for (int i = threadIdx.x; i < HW / 4; i += blockDim.x) dst[i] = (f4)(0.f);
    }
}

__global__ __launch_bounds__(256) void scatter_kernel(
    const float* __restrict__ emb, const float* __restrict__ mask,
    const int* __restrict__ loc, const float* __restrict__ Wp,
    const float* __restrict__ bp, float* __restrict__ out) {

    __shared__ float Ws[DIN][DSC];
    __shared__ float Es[32][DIN + 4];

    const int tid  = threadIdx.x;
    const int ent0 = blockIdx.x * 32;

    for (int i = tid; i < (DIN * DSC) / 4; i += 256)
        ((f4*)Ws)[i] = ((const f4*)Wp)[i];
    for (int i = tid; i < (32 * DIN) / 4; i += 256) {
        const int e  = i >> 6;
        const int k4 = i & 63;
        *(f4*)&Es[e][k4 * 4] =
            ((const f4*)(emb + (size_t)(ent0 + e) * DIN))[k4];
    }
    __syncthreads();

    const int g   = tid >> 3;
    const int dq  = (tid & 7) * 4;
    const int ent = ent0 + g;
    const int b   = ent >> 9;

    float ax = bp[dq + 0], ay = bp[dq + 1], az = bp[dq + 2], aw = bp[dq + 3];

    #pragma unroll 4
    for (int k = 0; k < DIN; k += 4) {
        const f4 ev = *(const f4*)&Es[g][k];
        const f4 w0 = *(const f4*)&Ws[k + 0][dq];
        const f4 w1 = *(const f4*)&Ws[k + 1][dq];
        const f4 w2 = *(const f4*)&Ws[k + 2][dq];
        const f4 w3 = *(const f4*)&Ws[k + 3][dq];
        ax = fmaf(ev.x, w0.x, fmaf(ev.y, w1.x, fmaf(ev.z, w2.x, fmaf(ev.w, w3.x, ax))));
        ay = fmaf(ev.x, w0.y, fmaf(ev.y, w1.y, fmaf(ev.z, w2.y, fmaf(ev.w, w3.y, ay))));
        az = fmaf(ev.x, w0.z, fmaf(ev.y, w1.z, fmaf(ev.z, w2.z, fmaf(ev.w, w3.z, az))));
        aw = fmaf(ev.x, w0.w, fmaf(ev.y, w1.w, fmaf(ev.z, w2.w, fmaf(ev.w, w3.w, aw))));
    }

    const float m = mask[ent];
    int y = loc[2 * ent + 0];
    int x = loc[2 * ent + 1];
    y = min(max(y, 0), Hh - 1);
    x = min(max(x, 0), Ww - 1);

    float* dst = out + ((size_t)b * COUT + Cc) * HW + (size_t)y * Ww + x;
    float v[4] = { ax, ay, az, aw };
    #pragma unroll
    for (int j = 0; j < 4; ++j) {
        const float r = fmaxf(v[j], 0.f) * m;
        if (r != 0.f)
            atomicAdd(dst + (size_t)(dq + j) * HW, r);
    }
}

// ---------------------------------------------------------------------------
extern "C" void kernel_launch(void* const* d_in, const int* in_sizes, int n_in,
                              void* d_out, int out_size, void* d_ws, size_t ws_size,
                              hipStream_t stream) {
    const float* spatial = (const float*)d_in[0];  // [B, C, H, W]
    const float* emb     = (const float*)d_in[1];  // [B, N, DIN]
    const float* mask    = (const float*)d_in[2];  // [B, N]
    const int*   loc     = (const int*)d_in[3];    // [B, N, 2]
    const float* Wp      = (const float*)d_in[4];  // [DIN, DSC]
    const float* bp      = (const float*)d_in[5];  // [DSC]
    float* out = (float*)d_out;                    // [B, COUT, H, W]

    const size_t need = (size_t)Bsz * Nn * DSC * sizeof(float)
                      + (size_t)Bsz * Nn * sizeof(int);
    if (ws_size >= need) {
        float* projws = (float*)d_ws;
        int*   idxws  = (int*)((char*)d_ws + (size_t)Bsz * Nn * DSC * sizeof(float));
        proj_kernel<<<PR_GRID, 256, 0, stream>>>(emb, mask, loc, Wp, bp,
                                                 projws, idxws);
        copy_gather_kernel<<<CP_GRID + GA_GRID, CP_THREAD, 0, stream>>>(
            spatial, projws, idxws, out);
    } else {
        init_out_kernel<<<Bsz * COUT, 256, 0, stream>>>(spatial, out);
        scatter_kernel<<<(Bsz * Nn) / 32, 256, 0, stream>>>(emb, mask, loc, Wp, bp, out);
    }
}

// Round 11
// 91.145 us; speedup vs baseline: 1.0035x; 1.0035x over previous
//
#include <hip/hip_runtime.h>

// Problem constants (from reference)
#define Bsz  32
#define Nn   512
#define DIN  256
#define DSC  32
#define Cc   48
#define Hh   152
#define Ww   160
#define HW   (Hh * Ww)        // 24320
#define COUT (Cc + DSC)       // 80
#define HALF (HW / 2)         // 12160 cells per half-plane
#define HP4  (HALF / 4)       // 3040 float4 per half-plane

// Copy geometry: linear over spatial (one contiguous 149 MB stream).
#define CP_N4     (Bsz * Cc * (HW / 4))   // 9,338,880 float4 to copy
#define CP_GRID   2048
#define CP_THREAD 256
#define CP_STRIDE (CP_GRID * CP_THREAD)   // 524,288 f4 = 8 MB sliding window
#define SLAB4     (Cc * (HW / 4))         // 291,840 f4 per batch copy-slab
#define SC4       ((COUT - Cc) * (HW / 4))// 194,560 f4 dst slab shift per batch
#define PR_GRID   ((Bsz * Nn) / 32)       // 512 proj blocks
#define GA_GRID   (Bsz * DSC * 2)         // 2048 gather blocks

// Native clang vector type — required by __builtin_nontemporal_*.
typedef float f4 __attribute__((ext_vector_type(4)));

// ---------------------------------------------------------------------------
// Kernel A: copy + proj, ZERO LDS (copy occupancy uncapped).
//  blocks [0, CP_GRID):       grid-stride sliding-window copy
//                             spatial -> out[:,0:48]; CACHED loads (spatial
//                             L3-resident across replays) + NT stores.
//  blocks [CP_GRID,+PR_GRID): proj = relu(emb @ W + b) * mask -> projws,
//                             cell idx -> idxws. Register-only: W rows read
//                             direct (L1/L2-hot 32 KB), emb f4 broadcast
//                             across each entity's 8 lanes. Runs in the
//                             copy's drain phase; K_B sees it complete.
// ---------------------------------------------------------------------------
__global__ __launch_bounds__(CP_THREAD, 4) void copy_proj_kernel(
    const float* __restrict__ spatial, const float* __restrict__ emb,
    const float* __restrict__ mask, const int* __restrict__ loc,
    const float* __restrict__ Wp, const float* __restrict__ bp,
    float* __restrict__ out, float* __restrict__ projws,
    int* __restrict__ idxws) {

    const int bid = blockIdx.x;
    const int tid = threadIdx.x;

    if (bid < CP_GRID) {                  // ---- sliding-window copy ----
        const f4* __restrict__ src = (const f4*)spatial;
        f4* __restrict__       dst = (f4*)out;
        unsigned i = (unsigned)bid * CP_THREAD + tid;
        #pragma unroll 1
        for (int k = 0; k < 4; ++k) {     // 16 of 17 rounds, 4-deep
            const unsigned i0 = i, i1 = i + CP_STRIDE,
                           i2 = i + 2 * CP_STRIDE, i3 = i + 3 * CP_STRIDE;
            const f4 a0 = src[i0];        // cached: L3-resident after replay 1
            const f4 a1 = src[i1];
            const f4 a2 = src[i2];
            const f4 a3 = src[i3];
            __builtin_nontemporal_store(a0, dst + i0 + (i0 / (unsigned)SLAB4) * SC4);
            __builtin_nontemporal_store(a1, dst + i1 + (i1 / (unsigned)SLAB4) * SC4);
            __builtin_nontemporal_store(a2, dst + i2 + (i2 / (unsigned)SLAB4) * SC4);
            __builtin_nontemporal_store(a3, dst + i3 + (i3 / (unsigned)SLAB4) * SC4);
            i += 4 * CP_STRIDE;
        }
        {                                 // round 17
            const f4 a = src[i];
            __builtin_nontemporal_store(a, dst + i + (i / (unsigned)SLAB4) * SC4);
            i += CP_STRIDE;
        }
        if (i < (unsigned)CP_N4) {        // partial tail
            const f4 a = src[i];
            __builtin_nontemporal_store(a, dst + i + (i / (unsigned)SLAB4) * SC4);
        }
        return;
    }

    // ---- proj (register-only) ----
    const int g    = tid >> 3;            // entity within block
    const int dq4  = tid & 7;             // f4-column in W / proj row
    const int ent  = (bid - CP_GRID) * 32 + g;

    const f4* __restrict__ erow = (const f4*)(emb + (size_t)ent * DIN);
    const f4* __restrict__ wf4  = (const f4*)Wp;   // W[k][4*dq4] at k*8+dq4

    const f4 bv = ((const f4*)bp)[dq4];
    float ax = bv.x, ay = bv.y, az = bv.z, aw = bv.w;

    #pragma unroll 4
    for (int k4 = 0; k4 < DIN / 4; ++k4) {
        const f4 ev = erow[k4];
        const int k = k4 * 4;
        const f4 w0 = wf4[(k + 0) * 8 + dq4];
        const f4 w1 = wf4[(k + 1) * 8 + dq4];
        const f4 w2 = wf4[(k + 2) * 8 + dq4];
        const f4 w3 = wf4[(k + 3) * 8 + dq4];
        ax = fmaf(ev.x, w0.x, fmaf(ev.y, w1.x, fmaf(ev.z, w2.x, fmaf(ev.w, w3.x, ax))));
        ay = fmaf(ev.x, w0.y, fmaf(ev.y, w1.y, fmaf(ev.z, w2.y, fmaf(ev.w, w3.y, ay))));
        az = fmaf(ev.x, w0.z, fmaf(ev.y, w1.z, fmaf(ev.z, w2.z, fmaf(ev.w, w3.z, az))));
        aw = fmaf(ev.x, w0.w, fmaf(ev.y, w1.w, fmaf(ev.z, w2.w, fmaf(ev.w, w3.w, aw))));
    }

    const float m = mask[ent];
    f4 r;
    r.x = fmaxf(ax, 0.f) * m;
    r.y = fmaxf(ay, 0.f) * m;
    r.z = fmaxf(az, 0.f) * m;
    r.w = fmaxf(aw, 0.f) * m;
    ((f4*)projws)[(size_t)ent * (DSC / 4) + dq4] = r;

    if (dq4 == 0) {
        int y = loc[2 * ent + 0];
        int x = loc[2 * ent + 1];
        y = min(max(y, 0), Hh - 1);
        x = min(max(x, 0), Ww - 1);
        idxws[ent] = y * Ww + x;
    }
}

// ---------------------------------------------------------------------------
// Kernel B: gather. Block = (b, scatter-channel c, half-plane). Zero a
// 48.6 KB LDS accumulator, scan the batch's 512 entity cells (2/thread),
// LDS-atomicAdd in-range contributions (zero values skipped — exact), then
// dump as one contiguous NT stream. Blocks ordered by dst address.
// ---------------------------------------------------------------------------
__global__ __launch_bounds__(256) void gather_kernel(
    const float* __restrict__ projws, const int* __restrict__ idxws,
    float* __restrict__ out) {

    __shared__ float facc[HALF];          // 48,640 B

    const int g    = blockIdx.x;          // 0 .. GA_GRID-1, dst-address order
    const int b    = g >> 6;
    const int c    = (g >> 1) & 31;
    const int lo   = (g & 1) * HALF;
    const int tid  = threadIdx.x;

    for (int i = tid; i < HP4; i += 256) ((f4*)facc)[i] = (f4)(0.f);
    __syncthreads();

    const int2 v = ((const int2*)(idxws + b * Nn))[tid];  // entities 2t, 2t+1
    {
        const int r0 = v.x - lo;
        if ((unsigned)r0 < (unsigned)HALF) {
            const float p = projws[((size_t)b * Nn + 2 * tid) * DSC + c];
            if (p != 0.f) atomicAdd(&facc[r0], p);
        }
        const int r1 = v.y - lo;
        if ((unsigned)r1 < (unsigned)HALF) {
            const float p = projws[((size_t)b * Nn + 2 * tid + 1) * DSC + c];
            if (p != 0.f) atomicAdd(&facc[r1], p);
        }
    }
    __syncthreads();

    f4* obase = (f4*)(out + ((size_t)(b * COUT + Cc + c)) * HW + lo);
    for (int i = tid; i < HP4; i += 256)
        __builtin_nontemporal_store(((const f4*)facc)[i], obase + i);
}

// ---------------------------------------------------------------------------
// Fallback path (only if ws_size too small): R1 design.
// ---------------------------------------------------------------------------
__global__ __launch_bounds__(256) void init_out_kernel(
    const float* __restrict__ spatial, float* __restrict__ out) {
    const int plane = blockIdx.x;
    const int b = plane / COUT;
    const int c = plane % COUT;
    f4* dst = (f4*)(out + (size_t)plane * HW);
    if (c < Cc) {
        const f4* src = (const f4*)(spatial + ((size_t)b * Cc + c) * HW);
        for (int i = threadIdx.x; i < HW / 4; i += blockDim.x) dst[i] = src[i];
    } else {
        for (int i = threadIdx.x; i < HW / 4; i += blockDim.x) dst[i] = (f4)(0.f);
    }
}

__global__ __launch_bounds__(256) void scatter_kernel(
    const float* __restrict__ emb, const float* __restrict__ mask,
    const int* __restrict__ loc, const float* __restrict__ Wp,
    const float* __restrict__ bp, float* __restrict__ out) {

    __shared__ float Ws[DIN][DSC];
    __shared__ float Es[32][DIN + 4];

    const int tid  = threadIdx.x;
    const int ent0 = blockIdx.x * 32;

    for (int i = tid; i < (DIN * DSC) / 4; i += 256)
        ((f4*)Ws)[i] = ((const f4*)Wp)[i];
    for (int i = tid; i < (32 * DIN) / 4; i += 256) {
        const int e  = i >> 6;
        const int k4 = i & 63;
        *(f4*)&Es[e][k4 * 4] =
            ((const f4*)(emb + (size_t)(ent0 + e) * DIN))[k4];
    }
    __syncthreads();

    const int g   = tid >> 3;
    const int dq  = (tid & 7) * 4;
    const int ent = ent0 + g;
    const int b   = ent >> 9;

    float ax = bp[dq + 0], ay = bp[dq + 1], az = bp[dq + 2], aw = bp[dq + 3];

    #pragma unroll 4
    for (int k = 0; k < DIN; k += 4) {
        const f4 ev = *(const f4*)&Es[g][k];
        const f4 w0 = *(const f4*)&Ws[k + 0][dq];
        const f4 w1 = *(const f4*)&Ws[k + 1][dq];
        const f4 w2 = *(const f4*)&Ws[k + 2][dq];
        const f4 w3 = *(const f4*)&Ws[k + 3][dq];
        ax = fmaf(ev.x, w0.x, fmaf(ev.y, w1.x, fmaf(ev.z, w2.x, fmaf(ev.w, w3.x, ax))));
        ay = fmaf(ev.x, w0.y, fmaf(ev.y, w1.y, fmaf(ev.z, w2.y, fmaf(ev.w, w3.y, ay))));
        az = fmaf(ev.x, w0.z, fmaf(ev.y, w1.z, fmaf(ev.z, w2.z, fmaf(ev.w, w3.z, az))));
        aw = fmaf(ev.x, w0.w, fmaf(ev.y, w1.w, fmaf(ev.z, w2.w, fmaf(ev.w, w3.w, aw))));
    }

    const float m = mask[ent];
    int y = loc[2 * ent + 0];
    int x = loc[2 * ent + 1];
    y = min(max(y, 0), Hh - 1);
    x = min(max(x, 0), Ww - 1);

    float* dst = out + ((size_t)b * COUT + Cc) * HW + (size_t)y * Ww + x;
    float v[4] = { ax, ay, az, aw };
    #pragma unroll
    for (int j = 0; j < 4; ++j) {
        const float r = fmaxf(v[j], 0.f) * m;
        if (r != 0.f)
            atomicAdd(dst + (size_t)(dq + j) * HW, r);
    }
}

// ---------------------------------------------------------------------------
extern "C" void kernel_launch(void* const* d_in, const int* in_sizes, int n_in,
                              void* d_out, int out_size, void* d_ws, size_t ws_size,
                              hipStream_t stream) {
    const float* spatial = (const float*)d_in[0];  // [B, C, H, W]
    const float* emb     = (const float*)d_in[1];  // [B, N, DIN]
    const float* mask    = (const float*)d_in[2];  // [B, N]
    const int*   loc     = (const int*)d_in[3];    // [B, N, 2]
    const float* Wp      = (const float*)d_in[4];  // [DIN, DSC]
    const float* bp      = (const float*)d_in[5];  // [DSC]
    float* out = (float*)d_out;                    // [B, COUT, H, W]

    const size_t need = (size_t)Bsz * Nn * DSC * sizeof(float)
                      + (size_t)Bsz * Nn * sizeof(int);
    if (ws_size >= need) {
        float* projws = (float*)d_ws;
        int*   idxws  = (int*)((char*)d_ws + (size_t)Bsz * Nn * DSC * sizeof(float));
        copy_proj_kernel<<<CP_GRID + PR_GRID, CP_THREAD, 0, stream>>>(
            spatial, emb, mask, loc, Wp, bp, out, projws, idxws);
        gather_kernel<<<GA_GRID, 256, 0, stream>>>(projws, idxws, out);
    } else {
        init_out_kernel<<<Bsz * COUT, 256, 0, stream>>>(spatial, out);
        scatter_kernel<<<(Bsz * Nn) / 32, 256, 0, stream>>>(emb, mask, loc, Wp, bp, out);
    }
}

// Round 12
// 81.170 us; speedup vs baseline: 1.1269x; 1.1229x over previous
//
#include <hip/hip_runtime.h>

// Problem constants (from reference)
#define Bsz  32
#define Nn   512
#define DIN  256
#define DSC  32
#define Cc   48
#define Hh   152
#define Ww   160
#define HW   (Hh * Ww)        // 24320
#define COUT (Cc + DSC)       // 80
#define HALF (HW / 2)         // 12160 cells per half-plane
#define HP4  (HALF / 4)       // 3040 float4 per half-plane

// Copy geometry: linear over spatial (one contiguous 149 MB stream).
#define CP_N4     (Bsz * Cc * (HW / 4))   // 9,338,880 float4 to copy
#define CP_GRID   2048
#define CP_THREAD 256
#define CP_STRIDE (CP_GRID * CP_THREAD)   // 524,288 f4 = 8 MB sliding window
#define SLAB4     (Cc * (HW / 4))         // 291,840 f4 per batch copy-slab
#define SC4       ((COUT - Cc) * (HW / 4))// 194,560 f4 dst slab shift per batch
#define PR_GRID   128                     // condensed proj blocks (128 ents each)
#define GA_GRID   (Bsz * DSC * 2)         // 2048 gather blocks

// Native clang vector type — required by __builtin_nontemporal_*.
typedef float f4 __attribute__((ext_vector_type(4)));

// ---------------------------------------------------------------------------
// Kernel A: proj + copy fused. PROJ BLOCKS FIRST (bid 0..127) — only 12.5%
// of resident block slots during the head phase (vs 50% at 512 blocks in R9),
// so the copy saturates from t=0; proj hides under the copy and is complete
// at the kernel boundary (ordering for K_B).
//  proj block: stage W once in 32 KB LDS, then 4 groups x 32 entities:
//              relu(emb @ W + b) * mask -> projws, cell idx -> idxws.
//              emb row f4 reads broadcast across each entity's 8 lanes.
//  copy block: grid-stride sliding-window copy spatial -> out[:,0:48];
//              CACHED loads (spatial stays L3-resident across graph replays)
//              + NT stores (write stream does not allocate/evict L3).
// ---------------------------------------------------------------------------
__global__ __launch_bounds__(CP_THREAD, 4) void proj_copy_kernel(
    const float* __restrict__ spatial, const float* __restrict__ emb,
    const float* __restrict__ mask, const int* __restrict__ loc,
    const float* __restrict__ Wp, const float* __restrict__ bp,
    float* __restrict__ out, float* __restrict__ projws,
    int* __restrict__ idxws) {

    __shared__ float Ws[DIN][DSC];        // 32 KB (used by proj blocks only)

    const int bid = blockIdx.x;
    const int tid = threadIdx.x;

    if (bid >= PR_GRID) {                 // ---- sliding-window copy ----
        const f4* __restrict__ src = (const f4*)spatial;
        f4* __restrict__       dst = (f4*)out;
        unsigned i = (unsigned)(bid - PR_GRID) * CP_THREAD + tid;
        #pragma unroll 1
        for (int k = 0; k < 4; ++k) {     // 16 of 17 rounds, 4-deep
            const unsigned i0 = i, i1 = i + CP_STRIDE,
                           i2 = i + 2 * CP_STRIDE, i3 = i + 3 * CP_STRIDE;
            const f4 a0 = src[i0];        // cached: L3-resident after replay 1
            const f4 a1 = src[i1];
            const f4 a2 = src[i2];
            const f4 a3 = src[i3];
            __builtin_nontemporal_store(a0, dst + i0 + (i0 / (unsigned)SLAB4) * SC4);
            __builtin_nontemporal_store(a1, dst + i1 + (i1 / (unsigned)SLAB4) * SC4);
            __builtin_nontemporal_store(a2, dst + i2 + (i2 / (unsigned)SLAB4) * SC4);
            __builtin_nontemporal_store(a3, dst + i3 + (i3 / (unsigned)SLAB4) * SC4);
            i += 4 * CP_STRIDE;
        }
        {                                 // round 17
            const f4 a = src[i];
            __builtin_nontemporal_store(a, dst + i + (i / (unsigned)SLAB4) * SC4);
            i += CP_STRIDE;
        }
        if (i < (unsigned)CP_N4) {        // partial tail
            const f4 a = src[i];
            __builtin_nontemporal_store(a, dst + i + (i / (unsigned)SLAB4) * SC4);
        }
        return;
    }

    // ---- proj: 128 entities per block, W staged once ----
    for (int i = tid; i < (DIN * DSC) / 4; i += 256)
        ((f4*)Ws)[i] = ((const f4*)Wp)[i];
    __syncthreads();

    const int g   = tid >> 3;             // entity-in-group
    const int dq  = (tid & 7) * 4;        // first of 4 output channels
    const int dq4 = tid & 7;

    const f4 bv = ((const f4*)bp)[dq4];

    #pragma unroll 1
    for (int grp = 0; grp < 4; ++grp) {
        const int ent = bid * 128 + grp * 32 + g;
        const f4* __restrict__ erow = (const f4*)(emb + (size_t)ent * DIN);

        float ax = bv.x, ay = bv.y, az = bv.z, aw = bv.w;

        #pragma unroll 4
        for (int k4 = 0; k4 < DIN / 4; ++k4) {
            const f4 ev = erow[k4];
            const int k = k4 * 4;
            const f4 w0 = *(const f4*)&Ws[k + 0][dq];
            const f4 w1 = *(const f4*)&Ws[k + 1][dq];
            const f4 w2 = *(const f4*)&Ws[k + 2][dq];
            const f4 w3 = *(const f4*)&Ws[k + 3][dq];
            ax = fmaf(ev.x, w0.x, fmaf(ev.y, w1.x, fmaf(ev.z, w2.x, fmaf(ev.w, w3.x, ax))));
            ay = fmaf(ev.x, w0.y, fmaf(ev.y, w1.y, fmaf(ev.z, w2.y, fmaf(ev.w, w3.y, ay))));
            az = fmaf(ev.x, w0.z, fmaf(ev.y, w1.z, fmaf(ev.z, w2.z, fmaf(ev.w, w3.z, az))));
            aw = fmaf(ev.x, w0.w, fmaf(ev.y, w1.w, fmaf(ev.z, w2.w, fmaf(ev.w, w3.w, aw))));
        }

        const float m = mask[ent];
        f4 r;
        r.x = fmaxf(ax, 0.f) * m;
        r.y = fmaxf(ay, 0.f) * m;
        r.z = fmaxf(az, 0.f) * m;
        r.w = fmaxf(aw, 0.f) * m;
        ((f4*)projws)[(size_t)ent * (DSC / 4) + dq4] = r;

        if (dq4 == 0) {
            int y = loc[2 * ent + 0];
            int x = loc[2 * ent + 1];
            y = min(max(y, 0), Hh - 1);
            x = min(max(x, 0), Ww - 1);
            idxws[ent] = y * Ww + x;
        }
    }
}

// ---------------------------------------------------------------------------
// Kernel B: gather. Block = (b, scatter-channel c, half-plane). Zero a
// 48.6 KB LDS accumulator, scan the batch's 512 entity cells (2/thread),
// LDS-atomicAdd in-range contributions (zero values skipped — exact), then
// dump as one contiguous NT stream. Blocks ordered by dst address.
// At 108 MB fabric traffic it runs at the ~6.3 TB/s ceiling (~17 us).
// ---------------------------------------------------------------------------
__global__ __launch_bounds__(256) void gather_kernel(
    const float* __restrict__ projws, const int* __restrict__ idxws,
    float* __restrict__ out) {

    __shared__ float facc[HALF];          // 48,640 B

    const int g    = blockIdx.x;          // 0 .. GA_GRID-1, dst-address order
    const int b    = g >> 6;
    const int c    = (g >> 1) & 31;
    const int lo   = (g & 1) * HALF;
    const int tid  = threadIdx.x;

    for (int i = tid; i < HP4; i += 256) ((f4*)facc)[i] = (f4)(0.f);
    __syncthreads();

    const int2 v = ((const int2*)(idxws + b * Nn))[tid];  // entities 2t, 2t+1
    {
        const int r0 = v.x - lo;
        if ((unsigned)r0 < (unsigned)HALF) {
            const float p = projws[((size_t)b * Nn + 2 * tid) * DSC + c];
            if (p != 0.f) atomicAdd(&facc[r0], p);
        }
        const int r1 = v.y - lo;
        if ((unsigned)r1 < (unsigned)HALF) {
            const float p = projws[((size_t)b * Nn + 2 * tid + 1) * DSC + c];
            if (p != 0.f) atomicAdd(&facc[r1], p);
        }
    }
    __syncthreads();

    f4* obase = (f4*)(out + ((size_t)(b * COUT + Cc + c)) * HW + lo);
    for (int i = tid; i < HP4; i += 256)
        __builtin_nontemporal_store(((const f4*)facc)[i], obase + i);
}

// ---------------------------------------------------------------------------
// Fallback path (only if ws_size too small): R1 design.
// ---------------------------------------------------------------------------
__global__ __launch_bounds__(256) void init_out_kernel(
    const float* __restrict__ spatial, float* __restrict__ out) {
    const int plane = blockIdx.x;
    const int b = plane / COUT;
    const int c = plane % COUT;
    f4* dst = (f4*)(out + (size_t)plane * HW);
    if (c < Cc) {
        const f4* src = (const f4*)(spatial + ((size_t)b * Cc + c) * HW);
        for (int i = threadIdx.x; i < HW / 4; i += blockDim.x) dst[i] = src[i];
    } else {
        for (int i = threadIdx.x; i < HW / 4; i += blockDim.x) dst[i] = (f4)(0.f);
    }
}

__global__ __launch_bounds__(256) void scatter_kernel(
    const float* __restrict__ emb, const float* __restrict__ mask,
    const int* __restrict__ loc, const float* __restrict__ Wp,
    const float* __restrict__ bp, float* __restrict__ out) {

    __shared__ float Ws[DIN][DSC];
    __shared__ float Es[32][DIN + 4];

    const int tid  = threadIdx.x;
    const int ent0 = blockIdx.x * 32;

    for (int i = tid; i < (DIN * DSC) / 4; i += 256)
        ((f4*)Ws)[i] = ((const f4*)Wp)[i];
    for (int i = tid; i < (32 * DIN) / 4; i += 256) {
        const int e  = i >> 6;
        const int k4 = i & 63;
        *(f4*)&Es[e][k4 * 4] =
            ((const f4*)(emb + (size_t)(ent0 + e) * DIN))[k4];
    }
    __syncthreads();

    const int g   = tid >> 3;
    const int dq  = (tid & 7) * 4;
    const int ent = ent0 + g;
    const int b   = ent >> 9;

    float ax = bp[dq + 0], ay = bp[dq + 1], az = bp[dq + 2], aw = bp[dq + 3];

    #pragma unroll 4
    for (int k = 0; k < DIN; k += 4) {
        const f4 ev = *(const f4*)&Es[g][k];
        const f4 w0 = *(const f4*)&Ws[k + 0][dq];
        const f4 w1 = *(const f4*)&Ws[k + 1][dq];
        const f4 w2 = *(const f4*)&Ws[k + 2][dq];
        const f4 w3 = *(const f4*)&Ws[k + 3][dq];
        ax = fmaf(ev.x, w0.x, fmaf(ev.y, w1.x, fmaf(ev.z, w2.x, fmaf(ev.w, w3.x, ax))));
        ay = fmaf(ev.x, w0.y, fmaf(ev.y, w1.y, fmaf(ev.z, w2.y, fmaf(ev.w, w3.y, ay))));
        az = fmaf(ev.x, w0.z, fmaf(ev.y, w1.z, fmaf(ev.z, w2.z, fmaf(ev.w, w3.z, az))));
        aw = fmaf(ev.x, w0.w, fmaf(ev.y, w1.w, fmaf(ev.z, w2.w, fmaf(ev.w, w3.w, aw))));
    }

    const float m = mask[ent];
    int y = loc[2 * ent + 0];
    int x = loc[2 * ent + 1];
    y = min(max(y, 0), Hh - 1);
    x = min(max(x, 0), Ww - 1);

    float* dst = out + ((size_t)b * COUT + Cc) * HW + (size_t)y * Ww + x;
    float v[4] = { ax, ay, az, aw };
    #pragma unroll
    for (int j = 0; j < 4; ++j) {
        const float r = fmaxf(v[j], 0.f) * m;
        if (r != 0.f)
            atomicAdd(dst + (size_t)(dq + j) * HW, r);
    }
}

// ---------------------------------------------------------------------------
extern "C" void kernel_launch(void* const* d_in, const int* in_sizes, int n_in,
                              void* d_out, int out_size, void* d_ws, size_t ws_size,
                              hipStream_t stream) {
    const float* spatial = (const float*)d_in[0];  // [B, C, H, W]
    const float* emb     = (const float*)d_in[1];  // [B, N, DIN]
    const float* mask    = (const float*)d_in[2];  // [B, N]
    const int*   loc     = (const int*)d_in[3];    // [B, N, 2]
    const float* Wp      = (const float*)d_in[4];  // [DIN, DSC]
    const float* bp      = (const float*)d_in[5];  // [DSC]
    float* out = (float*)d_out;                    // [B, COUT, H, W]

    const size_t need = (size_t)Bsz * Nn * DSC * sizeof(float)
                      + (size_t)Bsz * Nn * sizeof(int);
    if (ws_size >= need) {
        float* projws = (float*)d_ws;
        int*   idxws  = (int*)((char*)d_ws + (size_t)Bsz * Nn * DSC * sizeof(float));
        proj_copy_kernel<<<PR_GRID + CP_GRID, CP_THREAD, 0, stream>>>(
            spatial, emb, mask, loc, Wp, bp, out, projws, idxws);
        gather_kernel<<<GA_GRID, 256, 0, stream>>>(projws, idxws, out);
    } else {
        init_out_kernel<<<Bsz * COUT, 256, 0, stream>>>(spatial, out);
        scatter_kernel<<<(Bsz * Nn) / 32, 256, 0, stream>>>(emb, mask, loc, Wp, bp, out);
    }
}

// Round 13
// 71.624 us; speedup vs baseline: 1.2771x; 1.1333x over previous
//
#include <hip/hip_runtime.h>

// Problem constants (from reference)
#define Bsz  32
#define Nn   512
#define DIN  256
#define DSC  32
#define Cc   48
#define Hh   152
#define Ww   160
#define HW   (Hh * Ww)        // 24320
#define COUT (Cc + DSC)       // 80
#define HALF (HW / 2)         // 12160 cells per half-plane
#define HP4  (HALF / 4)       // 3040 float4 per half-plane

// Copy geometry: linear over spatial (one contiguous 149 MB stream).
#define CP_N4     (Bsz * Cc * (HW / 4))   // 9,338,880 float4 to copy
#define CP_GRID   2048
#define CP_THREAD 256
#define CP_STRIDE (CP_GRID * CP_THREAD)   // 524,288 f4 = 8 MB sliding window
#define SLAB4     (Cc * (HW / 4))         // 291,840 f4 per batch copy-slab
#define SC4       ((COUT - Cc) * (HW / 4))// 194,560 f4 dst slab shift per batch
#define PR_GRID   ((Bsz * Nn) / 32)       // 512 proj blocks

// Native clang vector type — required by __builtin_nontemporal_*.
typedef float f4 __attribute__((ext_vector_type(4)));

// ---------------------------------------------------------------------------
// Kernel A: proj + copy fused. Proj blocks first (bid 0..511) — short blocks,
// W LDS-staged; they hide under the copy ramp and CUs converge to pure copy.
//  Copy: CACHED loads (spatial is 149 MB < 256 MB L3 -> stays resident
//  across graph replays; reads served from Infinity Cache) + NT stores
//  (write stream does not allocate/evict L3). 4-deep batched per wave.
// ---------------------------------------------------------------------------
__global__ __launch_bounds__(CP_THREAD, 4) void proj_copy_kernel(
    const float* __restrict__ spatial, const float* __restrict__ emb,
    const float* __restrict__ mask, const int* __restrict__ loc,
    const float* __restrict__ Wp, const float* __restrict__ bp,
    float* __restrict__ out, float* __restrict__ projws,
    int* __restrict__ idxws) {

    __shared__ float Ws[DIN][DSC];        // 32 KB (proj blocks only)

    const int bid = blockIdx.x;
    const int tid = threadIdx.x;

    if (bid >= PR_GRID) {                 // ---- sliding-window copy ----
        const f4* __restrict__ src = (const f4*)spatial;
        f4* __restrict__       dst = (f4*)out;
        unsigned i = (bid - PR_GRID) * CP_THREAD + tid;
        #pragma unroll 1
        for (int k = 0; k < 4; ++k) {     // 16 of 17 rounds, 4-deep ILP
            const unsigned i0 = i, i1 = i + CP_STRIDE,
                           i2 = i + 2 * CP_STRIDE, i3 = i + 3 * CP_STRIDE;
            const f4 a0 = src[i0];        // cached: L3-resident after replay 1
            const f4 a1 = src[i1];
            const f4 a2 = src[i2];
            const f4 a3 = src[i3];
            __builtin_nontemporal_store(a0, dst + i0 + (i0 / (unsigned)SLAB4) * SC4);
            __builtin_nontemporal_store(a1, dst + i1 + (i1 / (unsigned)SLAB4) * SC4);
            __builtin_nontemporal_store(a2, dst + i2 + (i2 / (unsigned)SLAB4) * SC4);
            __builtin_nontemporal_store(a3, dst + i3 + (i3 / (unsigned)SLAB4) * SC4);
            i += 4 * CP_STRIDE;
        }
        {                                 // round 17
            const f4 a = src[i];
            __builtin_nontemporal_store(a, dst + i + (i / (unsigned)SLAB4) * SC4);
            i += CP_STRIDE;
        }
        if (i < (unsigned)CP_N4) {        // partial tail round
            const f4 a = src[i];
            __builtin_nontemporal_store(a, dst + i + (i / (unsigned)SLAB4) * SC4);
        }
        return;
    }

    // ---- proj ----
    const int ent0 = bid * 32;

    for (int i = tid; i < (DIN * DSC) / 4; i += 256)
        ((f4*)Ws)[i] = ((const f4*)Wp)[i];
    __syncthreads();

    const int g   = tid >> 3;             // entity within block
    const int dq  = (tid & 7) * 4;        // first of 4 output channels
    const int ent = ent0 + g;

    const f4* __restrict__ erow = (const f4*)(emb + (size_t)ent * DIN);

    float ax = bp[dq + 0], ay = bp[dq + 1], az = bp[dq + 2], aw = bp[dq + 3];

    #pragma unroll 4
    for (int k4 = 0; k4 < DIN / 4; ++k4) {
        const f4 ev = erow[k4];
        const int k = k4 * 4;
        const f4 w0 = *(const f4*)&Ws[k + 0][dq];
        const f4 w1 = *(const f4*)&Ws[k + 1][dq];
        const f4 w2 = *(const f4*)&Ws[k + 2][dq];
        const f4 w3 = *(const f4*)&Ws[k + 3][dq];
        ax = fmaf(ev.x, w0.x, fmaf(ev.y, w1.x, fmaf(ev.z, w2.x, fmaf(ev.w, w3.x, ax))));
        ay = fmaf(ev.x, w0.y, fmaf(ev.y, w1.y, fmaf(ev.z, w2.y, fmaf(ev.w, w3.y, ay))));
        az = fmaf(ev.x, w0.z, fmaf(ev.y, w1.z, fmaf(ev.z, w2.z, fmaf(ev.w, w3.z, az))));
        aw = fmaf(ev.x, w0.w, fmaf(ev.y, w1.w, fmaf(ev.z, w2.w, fmaf(ev.w, w3.w, aw))));
    }

    const float m = mask[ent];
    f4 r;
    r.x = fmaxf(ax, 0.f) * m;
    r.y = fmaxf(ay, 0.f) * m;
    r.z = fmaxf(az, 0.f) * m;
    r.w = fmaxf(aw, 0.f) * m;
    ((f4*)projws)[(size_t)ent * (DSC / 4) + (tid & 7)] = r;

    if ((tid & 7) == 0) {
        int y = loc[2 * ent + 0];
        int x = loc[2 * ent + 1];
        y = min(max(y, 0), Hh - 1);
        x = min(max(x, 0), Ww - 1);
        idxws[ent] = y * Ww + x;
    }
}

// ---------------------------------------------------------------------------
// Kernel B: gather. Block = (b, scatter-channel c, half-plane). Zero a
// 48.6 KB LDS accumulator, scan the batch's 512 entity cells (2/thread),
// LDS-atomicAdd in-range contributions (zero values skipped — exact), then
// dump as one contiguous NT stream. Blocks ordered by dst address.
// ---------------------------------------------------------------------------
__global__ __launch_bounds__(256) void gather_kernel(
    const float* __restrict__ projws, const int* __restrict__ idxws,
    float* __restrict__ out) {

    __shared__ float facc[HALF];          // 48,640 B

    const int g    = blockIdx.x;          // 0 .. Bsz*DSC*2-1, dst-address order
    const int b    = g >> 6;
    const int c    = (g >> 1) & 31;
    const int lo   = (g & 1) * HALF;
    const int tid  = threadIdx.x;

    for (int i = tid; i < HP4; i += 256) ((f4*)facc)[i] = (f4)(0.f);
    __syncthreads();

    const int2 v = ((const int2*)(idxws + b * Nn))[tid];  // entities 2t, 2t+1
    {
        const int r0 = v.x - lo;
        if ((unsigned)r0 < (unsigned)HALF) {
            const float p = projws[((size_t)b * Nn + 2 * tid) * DSC + c];
            if (p != 0.f) atomicAdd(&facc[r0], p);
        }
        const int r1 = v.y - lo;
        if ((unsigned)r1 < (unsigned)HALF) {
            const float p = projws[((size_t)b * Nn + 2 * tid + 1) * DSC + c];
            if (p != 0.f) atomicAdd(&facc[r1], p);
        }
    }
    __syncthreads();

    f4* obase = (f4*)(out + ((size_t)(b * COUT + Cc + c)) * HW + lo);
    for (int i = tid; i < HP4; i += 256)
        __builtin_nontemporal_store(((const f4*)facc)[i], obase + i);
}

// ---------------------------------------------------------------------------
// Fallback path (only if ws_size too small): R1 design.
// ---------------------------------------------------------------------------
__global__ __launch_bounds__(256) void init_out_kernel(
    const float* __restrict__ spatial, float* __restrict__ out) {
    const int plane = blockIdx.x;
    const int b = plane / COUT;
    const int c = plane % COUT;
    f4* dst = (f4*)(out + (size_t)plane * HW);
    if (c < Cc) {
        const f4* src = (const f4*)(spatial + ((size_t)b * Cc + c) * HW);
        for (int i = threadIdx.x; i < HW / 4; i += blockDim.x) dst[i] = src[i];
    } else {
        for (int i = threadIdx.x; i < HW / 4; i += blockDim.x) dst[i] = (f4)(0.f);
    }
}

__global__ __launch_bounds__(256) void scatter_kernel(
    const float* __restrict__ emb, const float* __restrict__ mask,
    const int* __restrict__ loc, const float* __restrict__ Wp,
    const float* __restrict__ bp, float* __restrict__ out) {

    __shared__ float Ws[DIN][DSC];
    __shared__ float Es[32][DIN + 4];

    const int tid  = threadIdx.x;
    const int ent0 = blockIdx.x * 32;

    for (int i = tid; i < (DIN * DSC) / 4; i += 256)
        ((f4*)Ws)[i] = ((const f4*)Wp)[i];
    for (int i = tid; i < (32 * DIN) / 4; i += 256) {
        const int e  = i >> 6;
        const int k4 = i & 63;
        *(f4*)&Es[e][k4 * 4] =
            ((const f4*)(emb + (size_t)(ent0 + e) * DIN))[k4];
    }
    __syncthreads();

    const int g   = tid >> 3;
    const int dq  = (tid & 7) * 4;
    const int ent = ent0 + g;
    const int b   = ent >> 9;

    float ax = bp[dq + 0], ay = bp[dq + 1], az = bp[dq + 2], aw = bp[dq + 3];

    #pragma unroll 4
    for (int k = 0; k < DIN; k += 4) {
        const f4 ev = *(const f4*)&Es[g][k];
        const f4 w0 = *(const f4*)&Ws[k + 0][dq];
        const f4 w1 = *(const f4*)&Ws[k + 1][dq];
        const f4 w2 = *(const f4*)&Ws[k + 2][dq];
        const f4 w3 = *(const f4*)&Ws[k + 3][dq];
        ax = fmaf(ev.x, w0.x, fmaf(ev.y, w1.x, fmaf(ev.z, w2.x, fmaf(ev.w, w3.x, ax))));
        ay = fmaf(ev.x, w0.y, fmaf(ev.y, w1.y, fmaf(ev.z, w2.y, fmaf(ev.w, w3.y, ay))));
        az = fmaf(ev.x, w0.z, fmaf(ev.y, w1.z, fmaf(ev.z, w2.z, fmaf(ev.w, w3.z, az))));
        aw = fmaf(ev.x, w0.w, fmaf(ev.y, w1.w, fmaf(ev.z, w2.w, fmaf(ev.w, w3.w, aw))));
    }

    const float m = mask[ent];
    int y = loc[2 * ent + 0];
    int x = loc[2 * ent + 1];
    y = min(max(y, 0), Hh - 1);
    x = min(max(x, 0), Ww - 1);

    float* dst = out + ((size_t)b * COUT + Cc) * HW + (size_t)y * Ww + x;
    float v[4] = { ax, ay, az, aw };
    #pragma unroll
    for (int j = 0; j < 4; ++j) {
        const float r = fmaxf(v[j], 0.f) * m;
        if (r != 0.f)
            atomicAdd(dst + (size_t)(dq + j) * HW, r);
    }
}

// ---------------------------------------------------------------------------
extern "C" void kernel_launch(void* const* d_in, const int* in_sizes, int n_in,
                              void* d_out, int out_size, void* d_ws, size_t ws_size,
                              hipStream_t stream) {
    const float* spatial = (const float*)d_in[0];  // [B, C, H, W]
    const float* emb     = (const float*)d_in[1];  // [B, N, DIN]
    const float* mask    = (const float*)d_in[2];  // [B, N]
    const int*   loc     = (const int*)d_in[3];    // [B, N, 2]
    const float* Wp      = (const float*)d_in[4];  // [DIN, DSC]
    const float* bp      = (const float*)d_in[5];  // [DSC]
    float* out = (float*)d_out;                    // [B, COUT, H, W]

    const size_t need = (size_t)Bsz * Nn * DSC * sizeof(float)
                      + (size_t)Bsz * Nn * sizeof(int);
    if (ws_size >= need) {
        float* projws = (float*)d_ws;
        int*   idxws  = (int*)((char*)d_ws + (size_t)Bsz * Nn * DSC * sizeof(float));
        proj_copy_kernel<<<PR_GRID + CP_GRID, CP_THREAD, 0, stream>>>(
            spatial, emb, mask, loc, Wp, bp, out, projws, idxws);
        gather_kernel<<<Bsz * DSC * 2, 256, 0, stream>>>(projws, idxws, out);
    } else {
        init_out_kernel<<<Bsz * COUT, 256, 0, stream>>>(spatial, out);
        scatter_kernel<<<(Bsz * Nn) / 32, 256, 0, stream>>>(emb, mask, loc, Wp, bp, out);
    }
}